// Round 6
// baseline (9461.870 us; speedup 1.0000x reference)
//
#include <hip/hip_runtime.h>

// ---------------------------------------------------------------------------
// 2-layer GRU, T=512, B=64, I=H=512, fp32. Persistent cooperative kernel:
// 256 WGs (1/CU) x 512 threads, layers wavefront-pipelined (513 grid-steps).
// Round 6: deep explicit A-load pipelining.
//  - 32 cached global_load_dwordx4 issued back-to-back into q[32] (asm, no
//    sc bits -> L1/L2-cached), then staged vmcnt(16)/vmcnt(0) waits around
//    the two FMA half-blocks. One exposed round-trip per step instead of ~8
//    (round 5 had VGPR_Count=32 -> ~2 loads in flight).
//  - h broadcast remains the round-5 fresh-address scheme: h1 ring in ws,
//    h2 straight to out[]; producers store write-through (sc0 sc1); one
//    agent acquire fence at kernel entry; consumers load cached.
//  - packed flags (256 x 4B): wave 0 polls all 256 with one dwordx4/lane.
// ---------------------------------------------------------------------------

typedef float f32x4 __attribute__((ext_vector_type(4)));
typedef unsigned u32x4 __attribute__((ext_vector_type(4)));

#define GB_B 64
#define GB_H 512
#define GB_K 512
#define GB_G 1536
#define GB_T 512
#define NWG 256
#define NTHR 512
#define BH (GB_B * GB_H)  // one step-slab: 32768 floats = 131 KB

// float-word offsets inside ws
#define OFF_FLAGS 0     // 256 packed u32 flags (1 KB)
#define OFF_RING1 1024  // 512 slabs of BH floats = 67.1 MB

// ---- coherence helpers ----------------------------------------------------
__device__ __forceinline__ void st_coh_f4(float* p, f32x4 v) {
  asm volatile("global_store_dwordx4 %0, %1, off sc0 sc1" ::"v"(p), "v"(v)
               : "memory");
}
__device__ __forceinline__ void st_coh_u32(unsigned* p, unsigned v) {
  asm volatile("global_store_dword %0, %1, off sc0 sc1" ::"v"(p), "v"(v)
               : "memory");
}
// 16B coherent load of 4 packed flags, NO wait — caller manages vmcnt.
#define LDC4U(dst, addr)                                  \
  asm volatile("global_load_dwordx4 %0, %1, off sc0 sc1" \
               : "=v"(dst)                                \
               : "v"(addr))
// 16B CACHED load, NO wait — caller manages vmcnt (issue-order semantics).
#define LDQ(dst, base, OFFS)                              \
  asm volatile("global_load_dwordx4 %0, %1, off offset:" OFFS \
               : "=v"(dst)                                \
               : "v"(base))

__global__ void gru_init(float* __restrict__ ws) {
  unsigned* fl = (unsigned*)(ws + OFF_FLAGS);
  st_coh_u32(&fl[threadIdx.x], 0u);  // 1 block x 256 threads
}

// 12-row FMA micro-tile: acc[r] += dot(a, Wrow[r][K0..K0+3])
__device__ __forceinline__ void fma12(const f32x4 a, const float* const* Wrow,
                                      float* acc, const int K0) {
#pragma unroll
  for (int r = 0; r < 12; ++r) {
    const float* wr = Wrow[r] + K0;
    float v = acc[r];
    v = fmaf(a.x, wr[0], v);
    v = fmaf(a.y, wr[1], v);
    v = fmaf(a.z, wr[2], v);
    v = fmaf(a.w, wr[3], v);
    acc[r] = v;
  }
}

__global__ __launch_bounds__(NTHR, 2) void gru_persist(
    const float* __restrict__ x, const float* __restrict__ h0,
    const float* __restrict__ w_ih, const float* __restrict__ w_hh,
    const float* __restrict__ b_ih, const float* __restrict__ b_hh,
    float* __restrict__ out, float* __restrict__ ws) {
  __shared__ float part[8][12][GB_B];  // 24 KB
  __shared__ float sh_h[GB_B][4];      // 1 KB transpose tile

  const int tid = threadIdx.x;
  const int lane = tid & 63;  // batch row
  const int wg = blockIdx.x;
  const int layer = wg >> 7;       // 0 = first GRU layer, 1 = second
  const int j0 = (wg & 127) << 2;  // 4 hidden cols per WG
  const int wave = __builtin_amdgcn_readfirstlane(tid >> 6);
  const int side = wave >> 2;         // 0 = input-side, 1 = hidden-side
  const int kbase = (wave & 3) << 7;  // K-quarter * 128

  unsigned* flags = (unsigned*)(ws + OFF_FLAGS);
  float* ring1 = ws + OFF_RING1;  // h1_t slabs, t = 0..511

  // Step-invariant weight row pointers (uniform -> scalar regs).
  const float* Wmat = (side ? w_hh : w_ih) + (size_t)layer * GB_G * GB_K;
  const float* Wrow[12];
#pragma unroll
  for (int gate = 0; gate < 3; ++gate)
#pragma unroll
    for (int jj = 0; jj < 4; ++jj)
      Wrow[gate * 4 + jj] =
          Wmat + (size_t)(gate * GB_H + j0 + jj) * GB_K + kbase;

  // Epilogue state: biases + own-column running h in registers (waves 0-3).
  float bx[3] = {0.f, 0.f, 0.f}, bh[3] = {0.f, 0.f, 0.f};
  float hreg = 0.f;
  if (wave < 4) {
    const int j = j0 + wave;
#pragma unroll
    for (int g = 0; g < 3; ++g) {
      bx[g] = b_ih[layer * GB_G + g * GB_H + j];
      bh[g] = b_hh[layer * GB_G + g * GB_H + j];
    }
    hreg = h0[((size_t)layer * GB_B + lane) * GB_H + j];
  }

  // Drop stale L1/L2 lines (poison / previous replay) before cached reads of
  // ring1/out slabs.
  __builtin_amdgcn_fence(__ATOMIC_ACQUIRE, "agent");
  __syncthreads();

  for (int s = 0; s <= GB_T; ++s) {
    const int t = layer ? s - 1 : s;
    const bool active = layer ? (s >= 1) : (s < GB_T);

    if (active) {
      // A-operand base: mutable slabs are fresh-address -> cached loads ok.
      const float* Abase;
      if (layer == 0)
        Abase = side ? (t ? ring1 + (size_t)(t - 1) * BH : h0)
                     : (x + (size_t)t * BH);
      else
        Abase = side ? (t ? out + (size_t)(t - 1) * BH : h0 + BH)
                     : (ring1 + (size_t)t * BH);
      const float* Arow = Abase + lane * GB_K + kbase;

      float acc[12];
#pragma unroll
      for (int c = 0; c < 12; ++c) acc[c] = 0.f;

      f32x4 q[32];
      LDQ(q[0], Arow, "0");     LDQ(q[1], Arow, "16");
      LDQ(q[2], Arow, "32");    LDQ(q[3], Arow, "48");
      LDQ(q[4], Arow, "64");    LDQ(q[5], Arow, "80");
      LDQ(q[6], Arow, "96");    LDQ(q[7], Arow, "112");
      LDQ(q[8], Arow, "128");   LDQ(q[9], Arow, "144");
      LDQ(q[10], Arow, "160");  LDQ(q[11], Arow, "176");
      LDQ(q[12], Arow, "192");  LDQ(q[13], Arow, "208");
      LDQ(q[14], Arow, "224");  LDQ(q[15], Arow, "240");
      LDQ(q[16], Arow, "256");  LDQ(q[17], Arow, "272");
      LDQ(q[18], Arow, "288");  LDQ(q[19], Arow, "304");
      LDQ(q[20], Arow, "320");  LDQ(q[21], Arow, "336");
      LDQ(q[22], Arow, "352");  LDQ(q[23], Arow, "368");
      LDQ(q[24], Arow, "384");  LDQ(q[25], Arow, "400");
      LDQ(q[26], Arow, "416");  LDQ(q[27], Arow, "432");
      LDQ(q[28], Arow, "448");  LDQ(q[29], Arow, "464");
      LDQ(q[30], Arow, "480");  LDQ(q[31], Arow, "496");

      asm volatile("s_waitcnt vmcnt(16)" ::: "memory");
      __builtin_amdgcn_sched_barrier(0);
#pragma unroll
      for (int u = 0; u < 16; ++u) fma12(q[u], Wrow, acc, u * 4);

      asm volatile("s_waitcnt vmcnt(0)" ::: "memory");
      __builtin_amdgcn_sched_barrier(0);
#pragma unroll
      for (int u = 16; u < 32; ++u) fma12(q[u], Wrow, acc, u * 4);

#pragma unroll
      for (int c = 0; c < 12; ++c) part[wave][c][lane] = acc[c];
    }
    __syncthreads();

    if (active && wave < 4) {  // epilogue: wave w handles col j = j0 + w
      float X[3], Hs[3];
#pragma unroll
      for (int gate = 0; gate < 3; ++gate) {
        const int c = gate * 4 + wave;
        X[gate] = part[0][c][lane] + part[1][c][lane] + part[2][c][lane] +
                  part[3][c][lane] + bx[gate];
        Hs[gate] = part[4][c][lane] + part[5][c][lane] + part[6][c][lane] +
                   part[7][c][lane] + bh[gate];
      }
      const float r = 1.f / (1.f + __expf(-(X[0] + Hs[0])));
      const float z = 1.f / (1.f + __expf(-(X[1] + Hs[1])));
      const float n = tanhf(X[2] + r * Hs[2]);
      const float hnew = (1.f - z) * n + z * hreg;
      hreg = hnew;
      sh_h[lane][wave] = hnew;
    }
    __syncthreads();

    // Wave 0: store the 64x4 h tile (write-through), then grid barrier.
    if (tid < 64) {
      if (active) {
        const f32x4 hv = *(const f32x4*)&sh_h[lane][0];
        float* dst = (layer ? out : ring1) + (size_t)t * BH;
        st_coh_f4(dst + lane * GB_H + j0, hv);
      }
      if (s < GB_T) {
        asm volatile("s_waitcnt vmcnt(0)" ::: "memory");  // h stores at L3
        if (tid == 0) st_coh_u32(&flags[wg], (unsigned)(s + 1));
        const unsigned tgt = (unsigned)(s + 1);
        const unsigned* fp = flags + lane * 4;
        for (;;) {
          u32x4 f;
          LDC4U(f, fp);
          asm volatile("s_waitcnt vmcnt(0)" ::: "memory");
          const int ok =
              (f.x >= tgt) && (f.y >= tgt) && (f.z >= tgt) && (f.w >= tgt);
          if (__all(ok)) break;
          __builtin_amdgcn_s_sleep(1);
        }
      }
    }
    __syncthreads();
  }
}

extern "C" void kernel_launch(void* const* d_in, const int* in_sizes, int n_in,
                              void* d_out, int out_size, void* d_ws,
                              size_t ws_size, hipStream_t stream) {
  const float* x = (const float*)d_in[0];
  const float* h0 = (const float*)d_in[1];
  const float* w_ih = (const float*)d_in[2];
  const float* w_hh = (const float*)d_in[3];
  const float* b_ih = (const float*)d_in[4];
  const float* b_hh = (const float*)d_in[5];
  float* out = (float*)d_out;
  float* ws = (float*)d_ws;

  gru_init<<<1, 256, 0, stream>>>(ws);

  void* args[] = {(void*)&x,    (void*)&h0,   (void*)&w_ih, (void*)&w_hh,
                  (void*)&b_ih, (void*)&b_hh, (void*)&out,  (void*)&ws};
  (void)hipLaunchCooperativeKernel((const void*)gru_persist, dim3(NWG),
                                   dim3(NTHR), args, 0, stream);
}

// Round 7
// 7880.422 us; speedup vs baseline: 1.2007x; 1.2007x over previous
//
#include <hip/hip_runtime.h>

// ---------------------------------------------------------------------------
// 2-layer GRU, T=512, B=64, I=H=512, fp32. Persistent cooperative kernel:
// 256 WGs (1/CU) x 512 threads, layers wavefront-pipelined (513 grid-steps).
// Round 7 (= round 5 + two fixes, asm burst of round 6 reverted):
//  - __launch_bounds__(512,1): 256-VGPR budget; plain-C q[32] staging lets
//    the compiler keep all 32 A-loads in flight (round 5 had VGPR=32 -> ~2
//    in flight -> ~16 serial L2/L3 round trips per step).
//  - split barrier domains: layer-1 WGs poll only layer-1's 128 flags
//    (they read nothing produced by layer 2); layer-2 polls both halves
//    (ring1[s] and its own out[s-1] both carry flag value s+1). Layer 1
//    free-runs; ring is T-deep so no overwrite hazard.
//  - h broadcast: fresh-address scheme (ring1 in ws, h2 -> out[]), producers
//    write-through sc0 sc1, consumers cached, one entry acquire fence.
// ---------------------------------------------------------------------------

typedef float f32x4 __attribute__((ext_vector_type(4)));
typedef unsigned u32x4 __attribute__((ext_vector_type(4)));

#define GB_B 64
#define GB_H 512
#define GB_K 512
#define GB_G 1536
#define GB_T 512
#define NWG 256
#define NTHR 512
#define BH (GB_B * GB_H)  // one step-slab: 32768 floats = 131 KB

// float-word offsets inside ws
#define OFF_FLAGS 0     // 256 packed u32 flags (1 KB)
#define OFF_RING1 1024  // 512 slabs of BH floats = 67.1 MB

// ---- coherence helpers ----------------------------------------------------
__device__ __forceinline__ void st_coh_f4(float* p, f32x4 v) {
  asm volatile("global_store_dwordx4 %0, %1, off sc0 sc1" ::"v"(p), "v"(v)
               : "memory");
}
__device__ __forceinline__ void st_coh_u32(unsigned* p, unsigned v) {
  asm volatile("global_store_dword %0, %1, off sc0 sc1" ::"v"(p), "v"(v)
               : "memory");
}
// 16B coherent load of 4 packed flags, NO wait — caller manages vmcnt.
#define LDC4U(dst, addr)                                  \
  asm volatile("global_load_dwordx4 %0, %1, off sc0 sc1" \
               : "=v"(dst)                                \
               : "v"(addr))

__global__ void gru_init(float* __restrict__ ws) {
  unsigned* fl = (unsigned*)(ws + OFF_FLAGS);
  st_coh_u32(&fl[threadIdx.x], 0u);  // 1 block x 256 threads
}

// 12-row FMA micro-tile: acc[r] += dot(a, Wrow[r][K0..K0+3])
__device__ __forceinline__ void fma12(const f32x4 a, const float* const* Wrow,
                                      float* acc, const int K0) {
#pragma unroll
  for (int r = 0; r < 12; ++r) {
    const float* wr = Wrow[r] + K0;
    float v = acc[r];
    v = fmaf(a.x, wr[0], v);
    v = fmaf(a.y, wr[1], v);
    v = fmaf(a.z, wr[2], v);
    v = fmaf(a.w, wr[3], v);
    acc[r] = v;
  }
}

__global__ __launch_bounds__(NTHR, 1) void gru_persist(
    const float* __restrict__ x, const float* __restrict__ h0,
    const float* __restrict__ w_ih, const float* __restrict__ w_hh,
    const float* __restrict__ b_ih, const float* __restrict__ b_hh,
    float* __restrict__ out, float* __restrict__ ws) {
  __shared__ float part[8][12][GB_B];  // 24 KB
  __shared__ float sh_h[GB_B][4];      // 1 KB transpose tile

  const int tid = threadIdx.x;
  const int lane = tid & 63;  // batch row
  const int wg = blockIdx.x;
  const int layer = wg >> 7;       // 0 = first GRU layer, 1 = second
  const int j0 = (wg & 127) << 2;  // 4 hidden cols per WG
  const int wave = __builtin_amdgcn_readfirstlane(tid >> 6);
  const int side = wave >> 2;         // 0 = input-side, 1 = hidden-side
  const int kbase = (wave & 3) << 7;  // K-quarter * 128

  unsigned* flags = (unsigned*)(ws + OFF_FLAGS);
  float* ring1 = ws + OFF_RING1;  // h1_t slabs, t = 0..511

  // Step-invariant weight row pointers (uniform -> scalar regs).
  const float* Wmat = (side ? w_hh : w_ih) + (size_t)layer * GB_G * GB_K;
  const float* Wrow[12];
#pragma unroll
  for (int gate = 0; gate < 3; ++gate)
#pragma unroll
    for (int jj = 0; jj < 4; ++jj)
      Wrow[gate * 4 + jj] =
          Wmat + (size_t)(gate * GB_H + j0 + jj) * GB_K + kbase;

  // Epilogue state: biases + own-column running h in registers (waves 0-3).
  float bx[3] = {0.f, 0.f, 0.f}, bh[3] = {0.f, 0.f, 0.f};
  float hreg = 0.f;
  if (wave < 4) {
    const int j = j0 + wave;
#pragma unroll
    for (int g = 0; g < 3; ++g) {
      bx[g] = b_ih[layer * GB_G + g * GB_H + j];
      bh[g] = b_hh[layer * GB_G + g * GB_H + j];
    }
    hreg = h0[((size_t)layer * GB_B + lane) * GB_H + j];
  }

  // Drop stale L1/L2 lines (poison / previous replay) before cached reads of
  // ring1/out slabs.
  __builtin_amdgcn_fence(__ATOMIC_ACQUIRE, "agent");
  __syncthreads();

  for (int s = 0; s <= GB_T; ++s) {
    const int t = layer ? s - 1 : s;
    const bool active = layer ? (s >= 1) : (s < GB_T);

    if (active) {
      // A-operand base: mutable slabs are fresh-address -> cached loads ok.
      const float* Abase;
      if (layer == 0)
        Abase = side ? (t ? ring1 + (size_t)(t - 1) * BH : h0)
                     : (x + (size_t)t * BH);
      else
        Abase = side ? (t ? out + (size_t)(t - 1) * BH : h0 + BH)
                     : (ring1 + (size_t)t * BH);
      const float* Arow = Abase + lane * GB_K + kbase;

      float acc[12];
#pragma unroll
      for (int c = 0; c < 12; ++c) acc[c] = 0.f;

      // Staged loads (plain C): with the 256-VGPR budget the compiler can
      // keep all 32 dwordx4 in flight before the FMA block needs q[0].
      f32x4 q[32];
#pragma unroll
      for (int u = 0; u < 32; ++u) q[u] = ((const f32x4*)Arow)[u];
#pragma unroll
      for (int u = 0; u < 32; ++u) fma12(q[u], Wrow, acc, u * 4);

#pragma unroll
      for (int c = 0; c < 12; ++c) part[wave][c][lane] = acc[c];
    }
    __syncthreads();

    if (active && wave < 4) {  // epilogue: wave w handles col j = j0 + w
      float X[3], Hs[3];
#pragma unroll
      for (int gate = 0; gate < 3; ++gate) {
        const int c = gate * 4 + wave;
        X[gate] = part[0][c][lane] + part[1][c][lane] + part[2][c][lane] +
                  part[3][c][lane] + bx[gate];
        Hs[gate] = part[4][c][lane] + part[5][c][lane] + part[6][c][lane] +
                   part[7][c][lane] + bh[gate];
      }
      const float r = 1.f / (1.f + __expf(-(X[0] + Hs[0])));
      const float z = 1.f / (1.f + __expf(-(X[1] + Hs[1])));
      const float n = tanhf(X[2] + r * Hs[2]);
      const float hnew = (1.f - z) * n + z * hreg;
      hreg = hnew;
      sh_h[lane][wave] = hnew;
    }
    __syncthreads();

    // Wave 0: store the 64x4 h tile (write-through), then grid barrier.
    // Barrier domains: layer-1 WGs wait only on layer-1 flags (they consume
    // nothing from layer 2); layer-2 WGs wait on both halves (ring1[s] and
    // out[s-1] both carry flag value s+1 when ready).
    if (tid < 64) {
      if (active) {
        const f32x4 hv = *(const f32x4*)&sh_h[lane][0];
        float* dst = (layer ? out : ring1) + (size_t)t * BH;
        st_coh_f4(dst + lane * GB_H + j0, hv);
      }
      if (s < GB_T) {
        asm volatile("s_waitcnt vmcnt(0)" ::: "memory");  // h stores at L3
        if (tid == 0) st_coh_u32(&flags[wg], (unsigned)(s + 1));
        const unsigned tgt = (unsigned)(s + 1);
        const unsigned* fp = flags + lane * 4;
        const bool mypoll = layer ? true : (lane < 32);
        for (;;) {
          u32x4 f;
          LDC4U(f, fp);
          asm volatile("s_waitcnt vmcnt(0)" ::: "memory");
          const int ok = (!mypoll) | ((f.x >= tgt) & (f.y >= tgt) &
                                      (f.z >= tgt) & (f.w >= tgt));
          if (__all(ok)) break;
          __builtin_amdgcn_s_sleep(1);
        }
      }
    }
    __syncthreads();
  }
}

extern "C" void kernel_launch(void* const* d_in, const int* in_sizes, int n_in,
                              void* d_out, int out_size, void* d_ws,
                              size_t ws_size, hipStream_t stream) {
  const float* x = (const float*)d_in[0];
  const float* h0 = (const float*)d_in[1];
  const float* w_ih = (const float*)d_in[2];
  const float* w_hh = (const float*)d_in[3];
  const float* b_ih = (const float*)d_in[4];
  const float* b_hh = (const float*)d_in[5];
  float* out = (float*)d_out;
  float* ws = (float*)d_ws;

  gru_init<<<1, 256, 0, stream>>>(ws);

  void* args[] = {(void*)&x,    (void*)&h0,   (void*)&w_ih, (void*)&w_hh,
                  (void*)&b_ih, (void*)&b_hh, (void*)&out,  (void*)&ws};
  (void)hipLaunchCooperativeKernel((const void*)gru_persist, dim3(NWG),
                                   dim3(NTHR), args, 0, stream);
}